// Round 15
// baseline (4207.496 us; speedup 1.0000x reference)
//
#include <hip/hip_runtime.h>
#include <math.h>

// Problem dims
#define T_LEN 128
#define B_SZ  64
#define AD    32
#define ZD    64
#define KMIX  16
#define HID   128

// ---------------- workspace layout ----------------
#define WS_B0 106496
#define WS_B1 107008
#define WS_Q  107520
#define WS_R  111616
#define WS_W  112640

// ---------------- output layout (floats) ----------------
#define OUT_MEANS   0
#define OUT_COVS    524288
#define OUT_NMEANS  34078720
#define OUT_NCOVS   34603008
#define OUT_MATA    68157440
#define OUT_MATC    101711872

__device__ __forceinline__ float sigmoidf_(float x){ return 1.0f/(1.0f + expf(-x)); }

__device__ __forceinline__ unsigned short f2bf(float f){
  unsigned u = __float_as_uint(f);
  u += 0x7FFFu + ((u >> 16) & 1u);
  return (unsigned short)(u >> 16);
}

#define F4FMA(acc, s, v) { (acc).x += (s)*(v).x; (acc).y += (s)*(v).y; (acc).z += (s)*(v).z; (acc).w += (s)*(v).w; }
#define F4FMS(acc, s, v) { (acc).x -= (s)*(v).x; (acc).y -= (s)*(v).y; (acc).z -= (s)*(v).z; (acc).w -= (s)*(v).w; }

// ============ prep: pack LSTM weights bf16 [k/2][512][2], biases, Q, R ============
__global__ __launch_bounds__(256) void prep_kernel(
    const float* __restrict__ Wih0, const float* __restrict__ Whh0,
    const float* __restrict__ bih0, const float* __restrict__ bhh0,
    const float* __restrict__ Wih1, const float* __restrict__ Whh1,
    const float* __restrict__ bih1, const float* __restrict__ bhh1,
    const float* __restrict__ QL,   const float* __restrict__ RL,
    float* __restrict__ ws)
{
  int idx = blockIdx.x*256 + threadIdx.x;
  unsigned short* w16 = (unsigned short*)ws;
  if (idx < 212992) {
    const float* src; int local, base, IN;
    if (idx < 16384)       { src = Wih0; local = idx;          base = 0;      IN = 32; }
    else if (idx < 81920)  { src = Whh0; local = idx - 16384;  base = 16384;  IN = 128; }
    else if (idx < 147456) { src = Wih1; local = idx - 81920;  base = 81920;  IN = 128; }
    else                   { src = Whh1; local = idx - 147456; base = 147456; IN = 128; }
    int pair = local >> 10, g = (local >> 1) & 511, lo = local & 1;
    int k = pair*2 + lo;
    w16[base + local] = f2bf(src[g*IN + k]);
  } else if (idx < 213504) {
    int g = idx - 212992; ws[WS_B0 + g] = bih0[g] + bhh0[g];
  } else if (idx < 214016) {
    int g = idx - 213504; ws[WS_B1 + g] = bih1[g] + bhh1[g];
  } else if (idx < 218112) {              // Q = QL QL^T + 1e-3 I
    int e = idx - 214016; int i = e >> 6, j = e & 63;
    float s = (i==j) ? 1e-3f : 0.f;
    for (int k = 0; k < 64; ++k) s += QL[i*64+k]*QL[j*64+k];
    ws[WS_Q + e] = s;
  } else if (idx < 219136) {              // R = RL RL^T + 1e-3 I
    int e = idx - 218112; int i = e >> 5, j = e & 31;
    float s = (i==j) ? 1e-3f : 0.f;
    for (int k = 0; k < 32; ++k) s += RL[i*32+k]*RL[j*32+k];
    ws[WS_R + e] = s;
  }
}

// ============ 2-layer LSTM + softmax head -> w[T][B][16] ============
// (unchanged from r14 — split-K over 1024 threads, coalesced bf16 reads)
__global__ __launch_bounds__(1024) void lstm_kernel(
    const float* __restrict__ as_, const float* __restrict__ ws,
    const float* __restrict__ linW, const float* __restrict__ linb,
    float* __restrict__ wout)
{
  const int b = blockIdx.x, tid = threadIdx.x;
  const int g = tid & 511, hf = tid >> 9;            // gate, K-half
  const unsigned* W0ih = (const unsigned*)ws;        // [16][512] pairs
  const unsigned* W0hh = W0ih + 16*512;              // [64][512]
  const unsigned* W1ih = W0hh + 64*512;              // [64][512]
  const unsigned* W1hh = W1ih + 64*512;              // [64][512]

  __shared__ float xs[2][32];
  __shared__ float h0[128];
  __shared__ float h1[128];
  __shared__ float gpart[2][512];
  __shared__ float lw[16*132];                        // linW, pad-132 rows

  for (int e = tid; e < 2048; e += 1024) lw[(e >> 7)*132 + (e & 127)] = linW[e];
  if (tid < 128) { h0[tid] = 0.f; h1[tid] = 0.f; }
  if (tid < 32)  xs[0][tid] = as_[(0*B_SZ + b)*AD + tid];
  float c0 = 0.f, c1 = 0.f;
  const float bias0 = (hf == 0) ? ws[WS_B0 + g] : 0.f;
  const float bias1 = (hf == 0) ? ws[WS_B1 + g] : 0.f;
  const float lbk = linb[tid & 15];
  __syncthreads();

  for (int t = 0; t < T_LEN; ++t) {
    const int cp = t & 1, np = cp ^ 1;
    { // gates layer 0, half hf
      float acc = bias0;
      const int k0i = hf*8, k0h = hf*32;
      #pragma unroll
      for (int kk = 0; kk < 8; ++kk) {
        const unsigned u = W0ih[(k0i+kk)*512 + g];
        acc += __uint_as_float(u << 16) * xs[cp][2*(k0i+kk)]
             + __uint_as_float(u & 0xFFFF0000u) * xs[cp][2*(k0i+kk)+1];
      }
      #pragma unroll 8
      for (int kk = 0; kk < 32; ++kk) {
        const unsigned u = W0hh[(k0h+kk)*512 + g];
        acc += __uint_as_float(u << 16) * h0[2*(k0h+kk)]
             + __uint_as_float(u & 0xFFFF0000u) * h0[2*(k0h+kk)+1];
      }
      gpart[hf][g] = acc;
    }
    __syncthreads();                                  // B1
    if (tid < 128) {
      float ig = sigmoidf_(gpart[0][tid]     + gpart[1][tid]);
      float fg = sigmoidf_(gpart[0][tid+128] + gpart[1][tid+128]);
      float gg = tanhf    (gpart[0][tid+256] + gpart[1][tid+256]);
      float og = sigmoidf_(gpart[0][tid+384] + gpart[1][tid+384]);
      c0 = fg*c0 + ig*gg;
      h0[tid] = og * tanhf(c0);
    } else if (tid >= 512 && tid < 544 && t+1 < T_LEN) {
      xs[np][tid-512] = as_[((t+1)*B_SZ + b)*AD + (tid-512)];
    }
    __syncthreads();                                  // B2
    { // gates layer 1, half hf
      float acc = bias1;
      const int k0 = hf*32;
      #pragma unroll 8
      for (int kk = 0; kk < 32; ++kk) {
        const unsigned u = W1ih[(k0+kk)*512 + g];
        acc += __uint_as_float(u << 16) * h0[2*(k0+kk)]
             + __uint_as_float(u & 0xFFFF0000u) * h0[2*(k0+kk)+1];
      }
      #pragma unroll 8
      for (int kk = 0; kk < 32; ++kk) {
        const unsigned u = W1hh[(k0+kk)*512 + g];
        acc += __uint_as_float(u << 16) * h1[2*(k0+kk)]
             + __uint_as_float(u & 0xFFFF0000u) * h1[2*(k0+kk)+1];
      }
      gpart[hf][g] = acc;
    }
    __syncthreads();                                  // B3
    if (tid < 128) {
      float ig = sigmoidf_(gpart[0][tid]     + gpart[1][tid]);
      float fg = sigmoidf_(gpart[0][tid+128] + gpart[1][tid+128]);
      float gg = tanhf    (gpart[0][tid+256] + gpart[1][tid+256]);
      float og = sigmoidf_(gpart[0][tid+384] + gpart[1][tid+384]);
      c1 = fg*c1 + ig*gg;
      h1[tid] = og * tanhf(c1);
    }
    __syncthreads();                                  // B4
    if (tid < 64) {
      const int k = tid & 15, q = tid >> 4;
      float acc = 0.f;
      const float* lr = &lw[k*132 + q*32];
      const float* hr = &h1[q*32];
      #pragma unroll 8
      for (int j = 0; j < 32; ++j) acc += lr[j] * hr[j];
      acc += __shfl_xor(acc, 16);
      acc += __shfl_xor(acc, 32);
      const float logit = acc + lbk;
      float m = logit;
      m = fmaxf(m, __shfl_xor(m, 1));
      m = fmaxf(m, __shfl_xor(m, 2));
      m = fmaxf(m, __shfl_xor(m, 4));
      m = fmaxf(m, __shfl_xor(m, 8));
      const float e = expf(logit - m);
      float s = e;
      s += __shfl_xor(s, 1); s += __shfl_xor(s, 2);
      s += __shfl_xor(s, 4); s += __shfl_xor(s, 8);
      if (tid < 16) wout[(t*B_SZ + b)*KMIX + k] = e / s;
    }
  }
}

// ============ mix (unchanged) ============
__global__ __launch_bounds__(256) void mix_kernel(
    const float* __restrict__ w, const float* __restrict__ AK,
    const float* __restrict__ CK, float* __restrict__ out)
{
  float* matA = out + OUT_MATA;
  float* matC = out + OUT_MATC;
  const int tb0 = blockIdx.x * 16;
  const int tid = threadIdx.x;
  __shared__ float wl[16][16];
  { int lt = tid >> 4, k = tid & 15; wl[lt][k] = w[(tb0 + lt)*16 + k]; }
  __syncthreads();

  for (int e = tid; e < ZD*ZD; e += 256) {
    float v[16];
    #pragma unroll
    for (int u = 0; u < 16; ++u) v[u] = 0.f;
    #pragma unroll 4
    for (int k = 0; k < 16; ++k) {
      float a = AK[k*ZD*ZD + e];
      #pragma unroll
      for (int u = 0; u < 16; ++u) v[u] += wl[u][k] * a;
    }
    #pragma unroll
    for (int u = 0; u < 16; ++u) matA[(size_t)(tb0+u)*(ZD*ZD) + e] = v[u];
  }
  for (int e = tid; e < AD*ZD; e += 256) {
    float v[16];
    #pragma unroll
    for (int u = 0; u < 16; ++u) v[u] = 0.f;
    #pragma unroll 4
    for (int k = 0; k < 16; ++k) {
      float a = CK[k*AD*ZD + e];
      #pragma unroll
      for (int u = 0; u < 16; ++u) v[u] += wl[u][k] * a;
    }
    #pragma unroll
    for (int u = 0; u < 16; ++u) matC[(size_t)(tb0+u)*(AD*ZD) + e] = v[u];
  }
}

// ============ Kalman filter: one block (512 thr, 8 waves) per batch ============
// r15: LDS-instruction-throughput bound (r14 model: 4800 wave-instr/step x
// 12cy = measured 57.6k cy). Retile all matmul phases to 4-row tiles
// (8-10.7 MACs/LDS-instr, was 2.7-5.3) + dedicated mean-column groups with
// compact mcol[] buffer (float4 reads instead of stride-68 scalars).
// Q back in LDS (r14's Q-in-regs was -40us). Phase pairing per r10/r13,
// 6 barriers. covnext = (A covp)A^T - (A W^T)(A W^T)^T + Q.
__global__ __launch_bounds__(512, 1) void kalman_kernel(
    const float* __restrict__ as_, const float* __restrict__ ws,
    float* __restrict__ out)
{
  const int b = blockIdx.x, tid = threadIdx.x;
  const float* Rm = ws + WS_R;
  const float* Qg = ws + WS_Q;
  const float* matA = out + OUT_MATA;
  const float* matC = out + OUT_MATC;
  float* means  = out + OUT_MEANS;
  float* covs   = out + OUT_COVS;
  float* nmeans = out + OUT_NMEANS;
  float* ncovs  = out + OUT_NCOVS;

  __shared__ __align__(16) float covp[64*68];   // col 64 = meanp; 65-67 = 0
  __shared__ __align__(16) float At[2][64*68];  // A^T, double-buffered
  __shared__ __align__(16) float Cm[2][32*68];  // C rows, stride 68
  __shared__ __align__(16) float CPm[32*68];    // [CP | Cmeanp - a]
  __shared__ __align__(16) float Wm[32*68];     // L^{-1} CPaug
  __shared__ float Smat[32*36];                 // S -> L (inv diag on diagonal)
  __shared__ __align__(16) float Um[64*68];     // A @ covp_aug
  __shared__ __align__(16) float Vt[32*68];     // Vt[a][i] = (A W^T)[i][a]
  __shared__ __align__(16) float Ql[64*68];     // Q staged
  __shared__ __align__(16) float mcol[64];      // compact copy of covp[:,64]

  // ---- init
  for (int e = tid; e < 64*68; e += 512) covp[e] = 0.f;
  __syncthreads();
  for (int e = tid; e < 64*64; e += 512) {
    const int i = e >> 6, j = e & 63;
    Ql[i*68 + j]   = Qg[e];
    covp[i*68 + j] = (i == j) ? 1.f : 0.f;
  }
  if (tid < 64) mcol[tid] = 0.f;
  {
    const float* Ag = matA + (size_t)b*4096;
    const float* Cg = matC + (size_t)b*2048;
    for (int e = tid; e < 4096; e += 512) At[0][(e & 63)*68 + (e >> 6)] = Ag[e];
    for (int e = tid; e < 2048; e += 512) Cm[0][(e >> 6)*68 + (e & 63)] = Cg[e];
  }
  __syncthreads();

  int cur = 0;
  for (int t = 0; t < T_LEN; ++t) {
    const int tb = t*B_SZ + b;
    const int nxt = cur ^ 1;

    // ---- PH1: CP = C @ covp  (tid<128: 4x4 tiles)  ||  mean col (tid 128-159)
    if (tid < 128) {
      const int i0 = (tid >> 4)*4, j0 = (tid & 15)*4;
      const float* Cb = Cm[cur];
      float4 a0 = make_float4(0,0,0,0), a1 = a0, a2 = a0, a3 = a0;
      #pragma unroll 4
      for (int k4 = 0; k4 < 16; ++k4) {
        const int k = k4*4;
        const float4 c0 = *(const float4*)&Cb[(i0+0)*68 + k];
        const float4 c1 = *(const float4*)&Cb[(i0+1)*68 + k];
        const float4 c2 = *(const float4*)&Cb[(i0+2)*68 + k];
        const float4 c3 = *(const float4*)&Cb[(i0+3)*68 + k];
        const float4 b0 = *(const float4*)&covp[(k+0)*68 + j0];
        const float4 b1 = *(const float4*)&covp[(k+1)*68 + j0];
        const float4 b2 = *(const float4*)&covp[(k+2)*68 + j0];
        const float4 b3 = *(const float4*)&covp[(k+3)*68 + j0];
        F4FMA(a0, c0.x, b0) F4FMA(a0, c0.y, b1) F4FMA(a0, c0.z, b2) F4FMA(a0, c0.w, b3)
        F4FMA(a1, c1.x, b0) F4FMA(a1, c1.y, b1) F4FMA(a1, c1.z, b2) F4FMA(a1, c1.w, b3)
        F4FMA(a2, c2.x, b0) F4FMA(a2, c2.y, b1) F4FMA(a2, c2.z, b2) F4FMA(a2, c2.w, b3)
        F4FMA(a3, c3.x, b0) F4FMA(a3, c3.y, b1) F4FMA(a3, c3.z, b2) F4FMA(a3, c3.w, b3)
      }
      *(float4*)&CPm[(i0+0)*68 + j0] = a0;
      *(float4*)&CPm[(i0+1)*68 + j0] = a1;
      *(float4*)&CPm[(i0+2)*68 + j0] = a2;
      *(float4*)&CPm[(i0+3)*68 + j0] = a3;
    } else if (tid < 160) {
      const int i = tid - 128;
      const float* Crow = &Cm[cur][i*68];
      float s = -as_[(size_t)tb*AD + i];
      #pragma unroll 4
      for (int k4 = 0; k4 < 16; ++k4) {
        const float4 c4 = *(const float4*)&Crow[k4*4];
        const float4 m4 = *(const float4*)&mcol[k4*4];
        s += c4.x*m4.x + c4.y*m4.y + c4.z*m4.z + c4.w*m4.w;
      }
      CPm[i*68 + 64] = s;                      // C meanp - a
    }
    __syncthreads();   // B1
    // ---- PH2: S = CP C^T + R  (tid<64: 4x4 tiles)
    if (tid < 64) {
      const int i0 = (tid >> 3)*4, j0 = (tid & 7)*4;
      float4 a0 = make_float4(0,0,0,0), a1 = a0, a2 = a0, a3 = a0;
      #pragma unroll 4
      for (int k4 = 0; k4 < 16; ++k4) {
        const int k = k4*4;
        const float4 p0 = *(const float4*)&CPm[(i0+0)*68 + k];
        const float4 p1 = *(const float4*)&CPm[(i0+1)*68 + k];
        const float4 p2 = *(const float4*)&CPm[(i0+2)*68 + k];
        const float4 p3 = *(const float4*)&CPm[(i0+3)*68 + k];
        const float4 c0 = *(const float4*)&Cm[cur][(j0+0)*68 + k];
        const float4 c1 = *(const float4*)&Cm[cur][(j0+1)*68 + k];
        const float4 c2 = *(const float4*)&Cm[cur][(j0+2)*68 + k];
        const float4 c3 = *(const float4*)&Cm[cur][(j0+3)*68 + k];
        a0.x += p0.x*c0.x + p0.y*c0.y + p0.z*c0.z + p0.w*c0.w;
        a0.y += p0.x*c1.x + p0.y*c1.y + p0.z*c1.z + p0.w*c1.w;
        a0.z += p0.x*c2.x + p0.y*c2.y + p0.z*c2.z + p0.w*c2.w;
        a0.w += p0.x*c3.x + p0.y*c3.y + p0.z*c3.z + p0.w*c3.w;
        a1.x += p1.x*c0.x + p1.y*c0.y + p1.z*c0.z + p1.w*c0.w;
        a1.y += p1.x*c1.x + p1.y*c1.y + p1.z*c1.z + p1.w*c1.w;
        a1.z += p1.x*c2.x + p1.y*c2.y + p1.z*c2.z + p1.w*c2.w;
        a1.w += p1.x*c3.x + p1.y*c3.y + p1.z*c3.z + p1.w*c3.w;
        a2.x += p2.x*c0.x + p2.y*c0.y + p2.z*c0.z + p2.w*c0.w;
        a2.y += p2.x*c1.x + p2.y*c1.y + p2.z*c1.z + p2.w*c1.w;
        a2.z += p2.x*c2.x + p2.y*c2.y + p2.z*c2.z + p2.w*c2.w;
        a2.w += p2.x*c3.x + p2.y*c3.y + p2.z*c3.z + p2.w*c3.w;
        a3.x += p3.x*c0.x + p3.y*c0.y + p3.z*c0.z + p3.w*c0.w;
        a3.y += p3.x*c1.x + p3.y*c1.y + p3.z*c1.z + p3.w*c1.w;
        a3.z += p3.x*c2.x + p3.y*c2.y + p3.z*c2.z + p3.w*c2.w;
        a3.w += p3.x*c3.x + p3.y*c3.y + p3.z*c3.z + p3.w*c3.w;
      }
      #pragma unroll
      for (int r = 0; r < 4; ++r) {
        const float4 av = (r==0)?a0:(r==1)?a1:(r==2)?a2:a3;
        Smat[(i0+r)*36 + j0+0] = av.x + Rm[(i0+r)*32 + j0+0];
        Smat[(i0+r)*36 + j0+1] = av.y + Rm[(i0+r)*32 + j0+1];
        Smat[(i0+r)*36 + j0+2] = av.z + Rm[(i0+r)*32 + j0+2];
        Smat[(i0+r)*36 + j0+3] = av.w + Rm[(i0+r)*32 + j0+3];
      }
    }
    __syncthreads();   // B2
    // ---- PH3: wave0 Cholesky || U = A@covp (tid 64-191, 4rx8c) || U-mean (192-207)
    {
      const int wv = tid >> 6, lane = tid & 63;
      if (wv == 0) {
        if (lane < 32) {
          float Lr[32];
          float invd = 0.f;   // static select only (runtime Lr[lane] = r3 bug)
          #pragma unroll
          for (int j = 0; j < 32; ++j) Lr[j] = Smat[lane*36 + j];
          #pragma unroll
          for (int k = 0; k < 32; ++k) {
            const float piv = __shfl(Lr[k], k);
            const float ir  = 1.0f / sqrtf(piv);
            const float lik = Lr[k] * ir;
            invd = (lane == k) ? ir : invd;
            #pragma unroll
            for (int j = k+1; j < 32; ++j) {
              const float ljk = __shfl(lik, j);
              Lr[j] -= lik * ljk;
            }
            Lr[k] = lik;
          }
          #pragma unroll
          for (int j = 0; j < 32; ++j)
            if (j < lane) Smat[lane*36 + j] = Lr[j];
          Smat[lane*36 + lane] = invd;
        }
      } else if (tid < 192) {
        const int u = tid - 64;
        const int r0 = (u >> 3)*4, qa = (u & 7)*4, qb = qa + 32;
        const float* Atc = At[cur];
        float4 pa0 = make_float4(0,0,0,0), pa1 = pa0, pa2 = pa0, pa3 = pa0;
        float4 pb0 = pa0, pb1 = pa0, pb2 = pa0, pb3 = pa0;
        #pragma unroll 8
        for (int k = 0; k < 64; ++k) {
          const float4 av = *(const float4*)&Atc[k*68 + r0];   // A[r0..r0+3][k]
          const float4 b0 = *(const float4*)&covp[k*68 + qa];
          const float4 b1 = *(const float4*)&covp[k*68 + qb];
          F4FMA(pa0, av.x, b0) F4FMA(pa1, av.y, b0) F4FMA(pa2, av.z, b0) F4FMA(pa3, av.w, b0)
          F4FMA(pb0, av.x, b1) F4FMA(pb1, av.y, b1) F4FMA(pb2, av.z, b1) F4FMA(pb3, av.w, b1)
        }
        *(float4*)&Um[(r0+0)*68 + qa] = pa0;
        *(float4*)&Um[(r0+1)*68 + qa] = pa1;
        *(float4*)&Um[(r0+2)*68 + qa] = pa2;
        *(float4*)&Um[(r0+3)*68 + qa] = pa3;
        *(float4*)&Um[(r0+0)*68 + qb] = pb0;
        *(float4*)&Um[(r0+1)*68 + qb] = pb1;
        *(float4*)&Um[(r0+2)*68 + qb] = pb2;
        *(float4*)&Um[(r0+3)*68 + qb] = pb3;
      } else if (tid < 208) {
        const int r0 = (tid - 192)*4;
        const float* Atc = At[cur];
        float s0=0.f, s1=0.f, s2=0.f, s3=0.f;
        #pragma unroll 4
        for (int k4 = 0; k4 < 16; ++k4) {
          const float4 m4 = *(const float4*)&mcol[k4*4];
          #pragma unroll
          for (int m = 0; m < 4; ++m) {
            const float mk = (m==0)?m4.x:(m==1)?m4.y:(m==2)?m4.z:m4.w;
            const float4 av = *(const float4*)&Atc[(k4*4+m)*68 + r0];
            s0 += av.x*mk; s1 += av.y*mk; s2 += av.z*mk; s3 += av.w*mk;
          }
        }
        Um[(r0+0)*68 + 64] = s0;
        Um[(r0+1)*68 + 64] = s1;
        Um[(r0+2)*68 + 64] = s2;
        Um[(r0+3)*68 + 64] = s3;
      }
    }
    __syncthreads();   // B3
    // ---- PH4: forward solve W = L^{-1} CPaug (tid<65)  ||  stage t+1 (tid>=128)
    {
      if (tid < 65) {
        const int c = tid;
        float s[32];
        #pragma unroll
        for (int i = 0; i < 32; ++i) s[i] = CPm[i*68 + c];
        #pragma unroll
        for (int k = 0; k < 32; ++k) {
          const float y = s[k] * Smat[k*36 + k];     // diag holds 1/L[k][k]
          Wm[k*68 + c] = y;
          #pragma unroll
          for (int i = k+1; i < 32; ++i)
            s[i] -= Smat[i*36 + k] * y;
        }
      } else if (tid >= 128 && t < T_LEN-1) {
        const int su = tid - 128;                 // 0..383
        const float* Ag = matA + (size_t)(tb+64)*4096;
        const float* Cg = matC + (size_t)(tb+64)*2048;
        const float4 q0 = *(const float4*)&Ag[su*4];
        const float4 q1 = *(const float4*)&Ag[(su+384)*4];
        const float4 q2 = (su < 256) ? *(const float4*)&Ag[(su+768)*4]
                                     : *(const float4*)&Cg[(su-256)*4];
        const float4 q3 = *(const float4*)&Cg[(su+128)*4];
        { const int c = su;       const int i = c>>4, j = (c&15)*4;
          At[nxt][(j+0)*68+i]=q0.x; At[nxt][(j+1)*68+i]=q0.y; At[nxt][(j+2)*68+i]=q0.z; At[nxt][(j+3)*68+i]=q0.w; }
        { const int c = su + 384; const int i = c>>4, j = (c&15)*4;
          At[nxt][(j+0)*68+i]=q1.x; At[nxt][(j+1)*68+i]=q1.y; At[nxt][(j+2)*68+i]=q1.z; At[nxt][(j+3)*68+i]=q1.w; }
        if (su < 256) { const int c = su + 768; const int i = c>>4, j = (c&15)*4;
          At[nxt][(j+0)*68+i]=q2.x; At[nxt][(j+1)*68+i]=q2.y; At[nxt][(j+2)*68+i]=q2.z; At[nxt][(j+3)*68+i]=q2.w; }
        else { const int cc = su - 256; *(float4*)&Cm[nxt][(cc>>4)*68 + (cc&15)*4] = q2; }
        { const int cc = su + 128;      *(float4*)&Cm[nxt][(cc>>4)*68 + (cc&15)*4] = q3; }
      }
    }
    __syncthreads();   // B4
    // ---- PH5: covt = covp - W^T W -> covs (tid<128: 4jx8c) || means (128-143)
    //           || Vt = W A^T (tid 256-319: 4ax8c)
    if (tid < 128) {
      const int j0 = (tid >> 3)*4, c0 = (tid & 7)*8;
      float4 x00 = make_float4(0,0,0,0), x01 = x00, x10 = x00, x11 = x00;
      float4 x20 = x00, x21 = x00, x30 = x00, x31 = x00;
      #pragma unroll 8
      for (int k = 0; k < 32; ++k) {
        const float4 wj = *(const float4*)&Wm[k*68 + j0];
        const float4 qa = *(const float4*)&Wm[k*68 + c0];
        const float4 qb = *(const float4*)&Wm[k*68 + c0 + 4];
        F4FMA(x00, wj.x, qa) F4FMA(x01, wj.x, qb)
        F4FMA(x10, wj.y, qa) F4FMA(x11, wj.y, qb)
        F4FMA(x20, wj.z, qa) F4FMA(x21, wj.z, qb)
        F4FMA(x30, wj.w, qa) F4FMA(x31, wj.w, qb)
      }
      #pragma unroll
      for (int r = 0; r < 4; ++r) {
        const float4 xa = (r==0)?x00:(r==1)?x10:(r==2)?x20:x30;
        const float4 xb = (r==0)?x01:(r==1)?x11:(r==2)?x21:x31;
        float4 ca = *(const float4*)&covp[(j0+r)*68 + c0];
        float4 cb = *(const float4*)&covp[(j0+r)*68 + c0 + 4];
        ca.x -= xa.x; ca.y -= xa.y; ca.z -= xa.z; ca.w -= xa.w;
        cb.x -= xb.x; cb.y -= xb.y; cb.z -= xb.z; cb.w -= xb.w;
        *(float4*)&covs[(size_t)tb*4096 + (j0+r)*64 + c0]     = ca;
        *(float4*)&covs[(size_t)tb*4096 + (j0+r)*64 + c0 + 4] = cb;
      }
    } else if (tid < 144) {
      const int i0 = (tid - 128)*4;
      float s0=0.f, s1=0.f, s2=0.f, s3=0.f;
      #pragma unroll 8
      for (int k = 0; k < 32; ++k) {
        const float4 wi = *(const float4*)&Wm[k*68 + i0];
        const float wm = Wm[k*68 + 64];
        s0 += wi.x*wm; s1 += wi.y*wm; s2 += wi.z*wm; s3 += wi.w*wm;
      }
      float4 mo;
      mo.x = covp[(i0+0)*68 + 64] - s0;
      mo.y = covp[(i0+1)*68 + 64] - s1;
      mo.z = covp[(i0+2)*68 + 64] - s2;
      mo.w = covp[(i0+3)*68 + 64] - s3;
      *(float4*)&means[(size_t)tb*64 + i0] = mo;
    } else if (tid >= 256 && tid < 320) {
      const int v = tid - 256;
      const int a0 = (v >> 3)*4, c0 = (v & 7)*8;
      const float* Atc = At[cur];
      float4 y00 = make_float4(0,0,0,0), y01 = y00, y10 = y00, y11 = y00;
      float4 y20 = y00, y21 = y00, y30 = y00, y31 = y00;
      #pragma unroll 4
      for (int k4 = 0; k4 < 16; ++k4) {
        const int k = k4*4;
        const float4 w0 = *(const float4*)&Wm[(a0+0)*68 + k];
        const float4 w1 = *(const float4*)&Wm[(a0+1)*68 + k];
        const float4 w2 = *(const float4*)&Wm[(a0+2)*68 + k];
        const float4 w3 = *(const float4*)&Wm[(a0+3)*68 + k];
        #pragma unroll
        for (int m = 0; m < 4; ++m) {
          const float4 ta = *(const float4*)&Atc[(k+m)*68 + c0];
          const float4 tb2 = *(const float4*)&Atc[(k+m)*68 + c0 + 4];
          const float w0m = (m==0)?w0.x:(m==1)?w0.y:(m==2)?w0.z:w0.w;
          const float w1m = (m==0)?w1.x:(m==1)?w1.y:(m==2)?w1.z:w1.w;
          const float w2m = (m==0)?w2.x:(m==1)?w2.y:(m==2)?w2.z:w2.w;
          const float w3m = (m==0)?w3.x:(m==1)?w3.y:(m==2)?w3.z:w3.w;
          F4FMA(y00, w0m, ta) F4FMA(y01, w0m, tb2)
          F4FMA(y10, w1m, ta) F4FMA(y11, w1m, tb2)
          F4FMA(y20, w2m, ta) F4FMA(y21, w2m, tb2)
          F4FMA(y30, w3m, ta) F4FMA(y31, w3m, tb2)
        }
      }
      *(float4*)&Vt[(a0+0)*68 + c0]     = y00;
      *(float4*)&Vt[(a0+0)*68 + c0 + 4] = y01;
      *(float4*)&Vt[(a0+1)*68 + c0]     = y10;
      *(float4*)&Vt[(a0+1)*68 + c0 + 4] = y11;
      *(float4*)&Vt[(a0+2)*68 + c0]     = y20;
      *(float4*)&Vt[(a0+2)*68 + c0 + 4] = y21;
      *(float4*)&Vt[(a0+3)*68 + c0]     = y30;
      *(float4*)&Vt[(a0+3)*68 + c0 + 4] = y31;
    }
    __syncthreads();   // B5
    // ---- PH6: covnext = U A^T - V V^T + Q -> covp (tid<256: 4x4 tiles)
    //           || mean_next (tid 256-271)
    if (tid < 256) {
      const int i0 = (tid >> 4)*4, j0 = (tid & 15)*4;
      const float* Atc = At[cur];
      float4 a0 = *(const float4*)&Ql[(i0+0)*68 + j0];
      float4 a1 = *(const float4*)&Ql[(i0+1)*68 + j0];
      float4 a2 = *(const float4*)&Ql[(i0+2)*68 + j0];
      float4 a3 = *(const float4*)&Ql[(i0+3)*68 + j0];
      #pragma unroll 4
      for (int k4 = 0; k4 < 16; ++k4) {
        const int k = k4*4;
        const float4 u0 = *(const float4*)&Um[(i0+0)*68 + k];
        const float4 u1 = *(const float4*)&Um[(i0+1)*68 + k];
        const float4 u2 = *(const float4*)&Um[(i0+2)*68 + k];
        const float4 u3 = *(const float4*)&Um[(i0+3)*68 + k];
        #pragma unroll
        for (int m = 0; m < 4; ++m) {
          const float4 at = *(const float4*)&Atc[(k+m)*68 + j0];  // A[j0..j0+3][k+m]
          const float u0m = (m==0)?u0.x:(m==1)?u0.y:(m==2)?u0.z:u0.w;
          const float u1m = (m==0)?u1.x:(m==1)?u1.y:(m==2)?u1.z:u1.w;
          const float u2m = (m==0)?u2.x:(m==1)?u2.y:(m==2)?u2.z:u2.w;
          const float u3m = (m==0)?u3.x:(m==1)?u3.y:(m==2)?u3.z:u3.w;
          F4FMA(a0, u0m, at) F4FMA(a1, u1m, at) F4FMA(a2, u2m, at) F4FMA(a3, u3m, at)
        }
      }
      #pragma unroll 8
      for (int a = 0; a < 32; ++a) {
        const float4 vi = *(const float4*)&Vt[a*68 + i0];
        const float4 vj = *(const float4*)&Vt[a*68 + j0];
        F4FMS(a0, vi.x, vj) F4FMS(a1, vi.y, vj) F4FMS(a2, vi.z, vj) F4FMS(a3, vi.w, vj)
      }
      *(float4*)&covp[(i0+0)*68 + j0] = a0;
      *(float4*)&covp[(i0+1)*68 + j0] = a1;
      *(float4*)&covp[(i0+2)*68 + j0] = a2;
      *(float4*)&covp[(i0+3)*68 + j0] = a3;
      *(float4*)&ncovs[(size_t)tb*4096 + (i0+0)*64 + j0] = a0;
      *(float4*)&ncovs[(size_t)tb*4096 + (i0+1)*64 + j0] = a1;
      *(float4*)&ncovs[(size_t)tb*4096 + (i0+2)*64 + j0] = a2;
      *(float4*)&ncovs[(size_t)tb*4096 + (i0+3)*64 + j0] = a3;
    } else if (tid < 272) {
      const int i0 = (tid - 256)*4;
      float s0 = Um[(i0+0)*68 + 64];
      float s1 = Um[(i0+1)*68 + 64];
      float s2 = Um[(i0+2)*68 + 64];
      float s3 = Um[(i0+3)*68 + 64];
      #pragma unroll 8
      for (int a = 0; a < 32; ++a) {
        const float4 vi = *(const float4*)&Vt[a*68 + i0];
        const float wm = Wm[a*68 + 64];
        s0 -= vi.x*wm; s1 -= vi.y*wm; s2 -= vi.z*wm; s3 -= vi.w*wm;
      }
      covp[(i0+0)*68 + 64] = s0;
      covp[(i0+1)*68 + 64] = s1;
      covp[(i0+2)*68 + 64] = s2;
      covp[(i0+3)*68 + 64] = s3;
      float4 mo = make_float4(s0, s1, s2, s3);
      *(float4*)&mcol[i0] = mo;
      *(float4*)&nmeans[(size_t)tb*64 + i0] = mo;
    }
    __syncthreads();   // B6
    cur = nxt;
  }
}

extern "C" void kernel_launch(void* const* d_in, const int* in_sizes, int n_in,
                              void* d_out, int out_size, void* d_ws, size_t ws_size,
                              hipStream_t stream) {
  const float* as_  = (const float*)d_in[0];
  const float* AK   = (const float*)d_in[1];
  const float* CK   = (const float*)d_in[2];
  const float* QL   = (const float*)d_in[3];
  const float* RL   = (const float*)d_in[4];
  const float* linW = (const float*)d_in[5];
  const float* linb = (const float*)d_in[6];
  const float* Wih0 = (const float*)d_in[7];
  const float* Whh0 = (const float*)d_in[8];
  const float* bih0 = (const float*)d_in[9];
  const float* bhh0 = (const float*)d_in[10];
  const float* Wih1 = (const float*)d_in[11];
  const float* Whh1 = (const float*)d_in[12];
  const float* bih1 = (const float*)d_in[13];
  const float* bhh1 = (const float*)d_in[14];
  float* out = (float*)d_out;
  float* ws  = (float*)d_ws;

  prep_kernel<<<856, 256, 0, stream>>>(Wih0, Whh0, bih0, bhh0,
                                       Wih1, Whh1, bih1, bhh1, QL, RL, ws);
  lstm_kernel<<<B_SZ, 1024, 0, stream>>>(as_, ws, linW, linb, ws + WS_W);
  mix_kernel<<<(T_LEN*B_SZ)/16, 256, 0, stream>>>(ws + WS_W, AK, CK, out);
  kalman_kernel<<<B_SZ, 512, 0, stream>>>(as_, ws, out);
}

// Round 16
// 3795.450 us; speedup vs baseline: 1.1086x; 1.1086x over previous
//
#include <hip/hip_runtime.h>
#include <math.h>

// Problem dims
#define T_LEN 128
#define B_SZ  64
#define AD    32
#define ZD    64
#define KMIX  16
#define HID   128

// ---------------- workspace layout ----------------
// bf16 weights (ushort), packed [K/2][512][2] per matrix (COALESCED: lane=gate):
//   W0IH ushort ofs 0      (16384)
//   W0HH ushort ofs 16384  (65536)
//   W1IH ushort ofs 81920  (65536)
//   W1HH ushort ofs 147456 (65536)
// float region (offsets in floats):
#define WS_B0 106496
#define WS_B1 107008
#define WS_Q  107520
#define WS_R  111616
#define WS_W  112640

// ---------------- output layout (floats) ----------------
#define OUT_MEANS   0
#define OUT_COVS    524288
#define OUT_NMEANS  34078720
#define OUT_NCOVS   34603008
#define OUT_MATA    68157440
#define OUT_MATC    101711872

__device__ __forceinline__ float sigmoidf_(float x){ return 1.0f/(1.0f + expf(-x)); }

__device__ __forceinline__ unsigned short f2bf(float f){
  unsigned u = __float_as_uint(f);
  u += 0x7FFFu + ((u >> 16) & 1u);
  return (unsigned short)(u >> 16);
}

// ============ prep: pack LSTM weights bf16 [k/2][512][2], biases, Q, R ============
__global__ __launch_bounds__(256) void prep_kernel(
    const float* __restrict__ Wih0, const float* __restrict__ Whh0,
    const float* __restrict__ bih0, const float* __restrict__ bhh0,
    const float* __restrict__ Wih1, const float* __restrict__ Whh1,
    const float* __restrict__ bih1, const float* __restrict__ bhh1,
    const float* __restrict__ QL,   const float* __restrict__ RL,
    float* __restrict__ ws)
{
  int idx = blockIdx.x*256 + threadIdx.x;
  unsigned short* w16 = (unsigned short*)ws;
  if (idx < 212992) {
    const float* src; int local, base, IN;
    if (idx < 16384)       { src = Wih0; local = idx;          base = 0;      IN = 32; }
    else if (idx < 81920)  { src = Whh0; local = idx - 16384;  base = 16384;  IN = 128; }
    else if (idx < 147456) { src = Wih1; local = idx - 81920;  base = 81920;  IN = 128; }
    else                   { src = Whh1; local = idx - 147456; base = 147456; IN = 128; }
    int pair = local >> 10, g = (local >> 1) & 511, lo = local & 1;
    int k = pair*2 + lo;
    w16[base + local] = f2bf(src[g*IN + k]);
  } else if (idx < 213504) {
    int g = idx - 212992; ws[WS_B0 + g] = bih0[g] + bhh0[g];
  } else if (idx < 214016) {
    int g = idx - 213504; ws[WS_B1 + g] = bih1[g] + bhh1[g];
  } else if (idx < 218112) {              // Q = QL QL^T + 1e-3 I
    int e = idx - 214016; int i = e >> 6, j = e & 63;
    float s = (i==j) ? 1e-3f : 0.f;
    for (int k = 0; k < 64; ++k) s += QL[i*64+k]*QL[j*64+k];
    ws[WS_Q + e] = s;
  } else if (idx < 219136) {              // R = RL RL^T + 1e-3 I
    int e = idx - 218112; int i = e >> 5, j = e & 31;
    float s = (i==j) ? 1e-3f : 0.f;
    for (int k = 0; k < 32; ++k) s += RL[i*32+k]*RL[j*32+k];
    ws[WS_R + e] = s;
  }
}

// ============ 2-layer LSTM + softmax head -> w[T][B][16] ============
// r14 split-K over 1024 threads (16 waves = 4/SIMD): thread (g, hf=tid>>9)
// computes half of gate g's dot chain; halves combined in the act phase via
// gpart[2][512]. Coalesced bf16 [k][512] weight reads. 4 barriers/step.
__global__ __launch_bounds__(1024) void lstm_kernel(
    const float* __restrict__ as_, const float* __restrict__ ws,
    const float* __restrict__ linW, const float* __restrict__ linb,
    float* __restrict__ wout)
{
  const int b = blockIdx.x, tid = threadIdx.x;
  const int g = tid & 511, hf = tid >> 9;            // gate, K-half
  const unsigned* W0ih = (const unsigned*)ws;        // [16][512] pairs
  const unsigned* W0hh = W0ih + 16*512;              // [64][512]
  const unsigned* W1ih = W0hh + 64*512;              // [64][512]
  const unsigned* W1hh = W1ih + 64*512;              // [64][512]

  __shared__ float xs[2][32];
  __shared__ float h0[128];
  __shared__ float h1[128];
  __shared__ float gpart[2][512];
  __shared__ float lw[16*132];                        // linW, pad-132 rows

  for (int e = tid; e < 2048; e += 1024) lw[(e >> 7)*132 + (e & 127)] = linW[e];
  if (tid < 128) { h0[tid] = 0.f; h1[tid] = 0.f; }
  if (tid < 32)  xs[0][tid] = as_[(0*B_SZ + b)*AD + tid];
  float c0 = 0.f, c1 = 0.f;
  const float bias0 = (hf == 0) ? ws[WS_B0 + g] : 0.f;
  const float bias1 = (hf == 0) ? ws[WS_B1 + g] : 0.f;
  const float lbk = linb[tid & 15];
  __syncthreads();

  for (int t = 0; t < T_LEN; ++t) {
    const int cp = t & 1, np = cp ^ 1;
    { // gates layer 0, half hf
      float acc = bias0;
      const int k0i = hf*8, k0h = hf*32;
      #pragma unroll
      for (int kk = 0; kk < 8; ++kk) {
        const unsigned u = W0ih[(k0i+kk)*512 + g];
        acc += __uint_as_float(u << 16) * xs[cp][2*(k0i+kk)]
             + __uint_as_float(u & 0xFFFF0000u) * xs[cp][2*(k0i+kk)+1];
      }
      #pragma unroll 8
      for (int kk = 0; kk < 32; ++kk) {
        const unsigned u = W0hh[(k0h+kk)*512 + g];
        acc += __uint_as_float(u << 16) * h0[2*(k0h+kk)]
             + __uint_as_float(u & 0xFFFF0000u) * h0[2*(k0h+kk)+1];
      }
      gpart[hf][g] = acc;
    }
    __syncthreads();                                  // B1
    if (tid < 128) {
      float ig = sigmoidf_(gpart[0][tid]     + gpart[1][tid]);
      float fg = sigmoidf_(gpart[0][tid+128] + gpart[1][tid+128]);
      float gg = tanhf    (gpart[0][tid+256] + gpart[1][tid+256]);
      float og = sigmoidf_(gpart[0][tid+384] + gpart[1][tid+384]);
      c0 = fg*c0 + ig*gg;
      h0[tid] = og * tanhf(c0);
    } else if (tid >= 512 && tid < 544 && t+1 < T_LEN) {
      xs[np][tid-512] = as_[((t+1)*B_SZ + b)*AD + (tid-512)];
    }
    __syncthreads();                                  // B2
    { // gates layer 1, half hf
      float acc = bias1;
      const int k0 = hf*32;
      #pragma unroll 8
      for (int kk = 0; kk < 32; ++kk) {
        const unsigned u = W1ih[(k0+kk)*512 + g];
        acc += __uint_as_float(u << 16) * h0[2*(k0+kk)]
             + __uint_as_float(u & 0xFFFF0000u) * h0[2*(k0+kk)+1];
      }
      #pragma unroll 8
      for (int kk = 0; kk < 32; ++kk) {
        const unsigned u = W1hh[(k0+kk)*512 + g];
        acc += __uint_as_float(u << 16) * h1[2*(k0+kk)]
             + __uint_as_float(u & 0xFFFF0000u) * h1[2*(k0+kk)+1];
      }
      gpart[hf][g] = acc;
    }
    __syncthreads();                                  // B3
    if (tid < 128) {
      float ig = sigmoidf_(gpart[0][tid]     + gpart[1][tid]);
      float fg = sigmoidf_(gpart[0][tid+128] + gpart[1][tid+128]);
      float gg = tanhf    (gpart[0][tid+256] + gpart[1][tid+256]);
      float og = sigmoidf_(gpart[0][tid+384] + gpart[1][tid+384]);
      c1 = fg*c1 + ig*gg;
      h1[tid] = og * tanhf(c1);
    }
    __syncthreads();                                  // B4
    if (tid < 64) {
      const int k = tid & 15, q = tid >> 4;
      float acc = 0.f;
      const float* lr = &lw[k*132 + q*32];
      const float* hr = &h1[q*32];
      #pragma unroll 8
      for (int j = 0; j < 32; ++j) acc += lr[j] * hr[j];
      acc += __shfl_xor(acc, 16);
      acc += __shfl_xor(acc, 32);
      const float logit = acc + lbk;
      float m = logit;
      m = fmaxf(m, __shfl_xor(m, 1));
      m = fmaxf(m, __shfl_xor(m, 2));
      m = fmaxf(m, __shfl_xor(m, 4));
      m = fmaxf(m, __shfl_xor(m, 8));
      const float e = expf(logit - m);
      float s = e;
      s += __shfl_xor(s, 1); s += __shfl_xor(s, 2);
      s += __shfl_xor(s, 4); s += __shfl_xor(s, 8);
      if (tid < 16) wout[(t*B_SZ + b)*KMIX + k] = e / s;
    }
  }
}

// ============ mix (unchanged) ============
__global__ __launch_bounds__(256) void mix_kernel(
    const float* __restrict__ w, const float* __restrict__ AK,
    const float* __restrict__ CK, float* __restrict__ out)
{
  float* matA = out + OUT_MATA;
  float* matC = out + OUT_MATC;
  const int tb0 = blockIdx.x * 16;
  const int tid = threadIdx.x;
  __shared__ float wl[16][16];
  { int lt = tid >> 4, k = tid & 15; wl[lt][k] = w[(tb0 + lt)*16 + k]; }
  __syncthreads();

  for (int e = tid; e < ZD*ZD; e += 256) {
    float v[16];
    #pragma unroll
    for (int u = 0; u < 16; ++u) v[u] = 0.f;
    #pragma unroll 4
    for (int k = 0; k < 16; ++k) {
      float a = AK[k*ZD*ZD + e];
      #pragma unroll
      for (int u = 0; u < 16; ++u) v[u] += wl[u][k] * a;
    }
    #pragma unroll
    for (int u = 0; u < 16; ++u) matA[(size_t)(tb0+u)*(ZD*ZD) + e] = v[u];
  }
  for (int e = tid; e < AD*ZD; e += 256) {
    float v[16];
    #pragma unroll
    for (int u = 0; u < 16; ++u) v[u] = 0.f;
    #pragma unroll 4
    for (int k = 0; k < 16; ++k) {
      float a = CK[k*AD*ZD + e];
      #pragma unroll
      for (int u = 0; u < 16; ++u) v[u] += wl[u][k] * a;
    }
    #pragma unroll
    for (int u = 0; u < 16; ++u) matC[(size_t)(tb0+u)*(AD*ZD) + e] = v[u];
  }
}

// ============ Kalman filter: one block (512 thr, 8 waves) per batch ============
// r16 = r13 kalman verbatim (best measured: 3022us). 2-row register tiles
// everywhere (the r15 4-row variant starved wave-parallelism and regressed);
// Q in LDS (r14 Q-in-regs regressed). Phase pairing per r10 (chol||U,
// solve||stage). covnext = (A covp)A^T - (A W^T)(A W^T)^T + Q. 6 barriers.
__global__ __launch_bounds__(512, 1) void kalman_kernel(
    const float* __restrict__ as_, const float* __restrict__ ws,
    float* __restrict__ out)
{
  const int b = blockIdx.x, tid = threadIdx.x;
  const float* Rm = ws + WS_R;
  const float* Qg = ws + WS_Q;
  const float* matA = out + OUT_MATA;
  const float* matC = out + OUT_MATC;
  float* means  = out + OUT_MEANS;
  float* covs   = out + OUT_COVS;
  float* nmeans = out + OUT_NMEANS;
  float* ncovs  = out + OUT_NCOVS;

  __shared__ __align__(16) float covp[64*68];   // aug: col 64 = meanp; 65-67 = 0
  __shared__ __align__(16) float At[2][64*68];  // A^T, double-buffered
  __shared__ __align__(16) float Cm[2][32*68];  // C rows, stride 68
  __shared__ __align__(16) float CPm[32*68];    // [CP | Cmeanp - a]
  __shared__ __align__(16) float Wm[32*68];     // L^{-1} CPaug
  __shared__ float Smat[32*36];                 // S -> L (inv diag on diagonal)
  __shared__ __align__(16) float Um[64*68];     // A @ covp_aug
  __shared__ __align__(16) float Vt[32*68];     // V^T: Vt[a][i] = (A W^T)[i][a]
  __shared__ __align__(16) float Ql[64*68];     // Q staged

  // ---- init
  for (int e = tid; e < 64*68; e += 512) covp[e] = 0.f;   // incl cols 64-67
  __syncthreads();
  for (int e = tid; e < 64*64; e += 512) {
    const int i = e >> 6, j = e & 63;
    Ql[i*68 + j]   = Qg[e];
    covp[i*68 + j] = (i == j) ? 1.f : 0.f;
  }
  {
    const float* Ag = matA + (size_t)b*4096;
    const float* Cg = matC + (size_t)b*2048;
    for (int e = tid; e < 4096; e += 512) At[0][(e & 63)*68 + (e >> 6)] = Ag[e];
    for (int e = tid; e < 2048; e += 512) Cm[0][(e >> 6)*68 + (e & 63)] = Cg[e];
  }
  __syncthreads();

  int cur = 0;
  for (int t = 0; t < T_LEN; ++t) {
    const int tb = t*B_SZ + b;
    const int nxt = cur ^ 1;

    // ---- PH1: CPaug = C @ covp_aug (2-row tiles; 256 threads)
    if (tid < 256) {
      const int i2 = (tid >> 4)*2, j0 = (tid & 15)*4;
      const bool do64 = ((tid & 15) == 15);
      const float* Cr0 = &Cm[cur][(i2+0)*68];
      const float* Cr1 = &Cm[cur][(i2+1)*68];
      float4 accA = make_float4(0,0,0,0), accB = accA;
      float s64a = 0.f, s64b = 0.f;
      #pragma unroll 4
      for (int k4 = 0; k4 < 16; ++k4) {
        const float4 a4 = *(const float4*)&Cr0[k4*4];
        const float4 c4 = *(const float4*)&Cr1[k4*4];
        const float4 b0 = *(const float4*)&covp[(k4*4+0)*68 + j0];
        const float4 b1 = *(const float4*)&covp[(k4*4+1)*68 + j0];
        const float4 b2 = *(const float4*)&covp[(k4*4+2)*68 + j0];
        const float4 b3 = *(const float4*)&covp[(k4*4+3)*68 + j0];
        accA.x += a4.x*b0.x + a4.y*b1.x + a4.z*b2.x + a4.w*b3.x;
        accA.y += a4.x*b0.y + a4.y*b1.y + a4.z*b2.y + a4.w*b3.y;
        accA.z += a4.x*b0.z + a4.y*b1.z + a4.z*b2.z + a4.w*b3.z;
        accA.w += a4.x*b0.w + a4.y*b1.w + a4.z*b2.w + a4.w*b3.w;
        accB.x += c4.x*b0.x + c4.y*b1.x + c4.z*b2.x + c4.w*b3.x;
        accB.y += c4.x*b0.y + c4.y*b1.y + c4.z*b2.y + c4.w*b3.y;
        accB.z += c4.x*b0.z + c4.y*b1.z + c4.z*b2.z + c4.w*b3.z;
        accB.w += c4.x*b0.w + c4.y*b1.w + c4.z*b2.w + c4.w*b3.w;
        if (do64) {
          const float m0 = covp[(k4*4+0)*68+64], m1 = covp[(k4*4+1)*68+64];
          const float m2 = covp[(k4*4+2)*68+64], m3 = covp[(k4*4+3)*68+64];
          s64a += a4.x*m0 + a4.y*m1 + a4.z*m2 + a4.w*m3;
          s64b += c4.x*m0 + c4.y*m1 + c4.z*m2 + c4.w*m3;
        }
      }
      *(float4*)&CPm[(i2+0)*68 + j0] = accA;
      *(float4*)&CPm[(i2+1)*68 + j0] = accB;
      if (do64) {
        const float2 av = *(const float2*)&as_[(size_t)tb*AD + i2];
        CPm[(i2+0)*68 + 64] = s64a - av.x;       // C meanp - a
        CPm[(i2+1)*68 + 64] = s64b - av.y;
      }
    }
    __syncthreads();   // B1
    // ---- PH2: S = CP C^T + R, 2x2 tiles (256 threads)
    if (tid < 256) {
      const int i2 = (tid >> 4)*2, j2 = (tid & 15)*2;
      const float* cpr0 = &CPm[(i2+0)*68];
      const float* cpr1 = &CPm[(i2+1)*68];
      const float* cr0  = &Cm[cur][(j2+0)*68];
      const float* cr1  = &Cm[cur][(j2+1)*68];
      float s00=0,s01=0,s10=0,s11=0;
      #pragma unroll 4
      for (int k4 = 0; k4 < 16; ++k4) {
        const float4 p0 = *(const float4*)&cpr0[k4*4];
        const float4 p1 = *(const float4*)&cpr1[k4*4];
        const float4 c0 = *(const float4*)&cr0[k4*4];
        const float4 c1 = *(const float4*)&cr1[k4*4];
        s00 += p0.x*c0.x + p0.y*c0.y + p0.z*c0.z + p0.w*c0.w;
        s01 += p0.x*c1.x + p0.y*c1.y + p0.z*c1.z + p0.w*c1.w;
        s10 += p1.x*c0.x + p1.y*c0.y + p1.z*c0.z + p1.w*c0.w;
        s11 += p1.x*c1.x + p1.y*c1.y + p1.z*c1.z + p1.w*c1.w;
      }
      Smat[(i2+0)*36 + j2+0] = s00 + Rm[(i2+0)*32 + j2+0];
      Smat[(i2+0)*36 + j2+1] = s01 + Rm[(i2+0)*32 + j2+1];
      Smat[(i2+1)*36 + j2+0] = s10 + Rm[(i2+1)*32 + j2+0];
      Smat[(i2+1)*36 + j2+1] = s11 + Rm[(i2+1)*32 + j2+1];
    }
    __syncthreads();   // B2
    // ---- PH3: wave 0 Cholesky  ||  tid 64..511: U = A @ covp_aug
    //      (row-pair layout: 32 pairs x 14 groups; quads {g, g+14 if g<3};
    //       A read as float2 — At rows adjacent; covp reads near-broadcast)
    {
      const int wv = tid >> 6, lane = tid & 63;
      if (wv == 0) {
        if (lane < 32) {
          float Lr[32];
          float invd = 0.f;   // static select only (runtime Lr[lane] = r3 bug)
          #pragma unroll
          for (int j = 0; j < 32; ++j) Lr[j] = Smat[lane*36 + j];
          #pragma unroll
          for (int k = 0; k < 32; ++k) {
            const float piv = __shfl(Lr[k], k);
            const float ir  = 1.0f / sqrtf(piv);
            const float lik = Lr[k] * ir;
            invd = (lane == k) ? ir : invd;
            #pragma unroll
            for (int j = k+1; j < 32; ++j) {
              const float ljk = __shfl(lik, j);   // source lanes 0-31 all active
              Lr[j] -= lik * ljk;
            }
            Lr[k] = lik;
          }
          #pragma unroll
          for (int j = 0; j < 32; ++j)
            if (j < lane) Smat[lane*36 + j] = Lr[j];
          Smat[lane*36 + lane] = invd;
        }
      } else {
        const int su = tid - 64;                  // 0..447
        const int row2 = (su & 31)*2, g = su >> 5; // g 0..13
        const int q0c = g*4, q1c = (g+14)*4;       // q1 valid for g<3 (quads 14,15,16)
        const float* Atc = At[cur];
        float4 acc0 = make_float4(0,0,0,0), acc1 = acc0, acc2 = acc0, acc3 = acc0;
        #pragma unroll 8
        for (int k = 0; k < 64; ++k) {
          const float2 a2 = *(const float2*)&Atc[k*68 + row2];
          const float4 b0 = *(const float4*)&covp[k*68 + q0c];
          acc0.x += a2.x*b0.x; acc0.y += a2.x*b0.y; acc0.z += a2.x*b0.z; acc0.w += a2.x*b0.w;
          acc1.x += a2.y*b0.x; acc1.y += a2.y*b0.y; acc1.z += a2.y*b0.z; acc1.w += a2.y*b0.w;
          if (g < 3) {
            const float4 b1 = *(const float4*)&covp[k*68 + q1c];
            acc2.x += a2.x*b1.x; acc2.y += a2.x*b1.y; acc2.z += a2.x*b1.z; acc2.w += a2.x*b1.w;
            acc3.x += a2.y*b1.x; acc3.y += a2.y*b1.y; acc3.z += a2.y*b1.z; acc3.w += a2.y*b1.w;
          }
        }
        *(float4*)&Um[(row2+0)*68 + q0c] = acc0;
        *(float4*)&Um[(row2+1)*68 + q0c] = acc1;
        if (g < 3) {
          *(float4*)&Um[(row2+0)*68 + q1c] = acc2;
          *(float4*)&Um[(row2+1)*68 + q1c] = acc3;
        }
      }
    }
    __syncthreads();   // B3
    // ---- PH4: forward solve W = L^{-1} CPaug (tid<65)  ||  stage t+1 (tid>=128)
    {
      if (tid < 65) {
        const int c = tid;
        float s[32];
        #pragma unroll
        for (int i = 0; i < 32; ++i) s[i] = CPm[i*68 + c];
        #pragma unroll
        for (int k = 0; k < 32; ++k) {
          const float y = s[k] * Smat[k*36 + k];     // diag holds 1/L[k][k]
          Wm[k*68 + c] = y;
          #pragma unroll
          for (int i = k+1; i < 32; ++i)
            s[i] -= Smat[i*36 + k] * y;
        }
      } else if (tid >= 128 && t < T_LEN-1) {
        const int su = tid - 128;                 // 0..383
        const float* Ag = matA + (size_t)(tb+64)*4096;
        const float* Cg = matC + (size_t)(tb+64)*2048;
        const float4 q0 = *(const float4*)&Ag[su*4];
        const float4 q1 = *(const float4*)&Ag[(su+384)*4];
        const float4 q2 = (su < 256) ? *(const float4*)&Ag[(su+768)*4]
                                     : *(const float4*)&Cg[(su-256)*4];
        const float4 q3 = *(const float4*)&Cg[(su+128)*4];
        { const int c = su;       const int i = c>>4, j = (c&15)*4;
          At[nxt][(j+0)*68+i]=q0.x; At[nxt][(j+1)*68+i]=q0.y; At[nxt][(j+2)*68+i]=q0.z; At[nxt][(j+3)*68+i]=q0.w; }
        { const int c = su + 384; const int i = c>>4, j = (c&15)*4;
          At[nxt][(j+0)*68+i]=q1.x; At[nxt][(j+1)*68+i]=q1.y; At[nxt][(j+2)*68+i]=q1.z; At[nxt][(j+3)*68+i]=q1.w; }
        if (su < 256) { const int c = su + 768; const int i = c>>4, j = (c&15)*4;
          At[nxt][(j+0)*68+i]=q2.x; At[nxt][(j+1)*68+i]=q2.y; At[nxt][(j+2)*68+i]=q2.z; At[nxt][(j+3)*68+i]=q2.w; }
        else { const int cc = su - 256; *(float4*)&Cm[nxt][(cc>>4)*68 + (cc&15)*4] = q2; }
        { const int cc = su + 128;      *(float4*)&Cm[nxt][(cc>>4)*68 + (cc&15)*4] = q3; }
      }
    }
    __syncthreads();   // B4
    // ---- PH5: covt = covp - W^T W -> covs/means (tid<256, 2-row tiles)
    //           ||  Vt[a][i] = sum_k W[a][k] A[i][k] (tid>=256, 2-row tiles)
    if (tid < 256) {
      const int j2 = (tid >> 3)*2, c0 = (tid & 7)*8;
      const bool do64 = ((tid & 7) == 7);
      float4 a0 = make_float4(0,0,0,0), a1 = a0, b0a = a0, b1a = a0;
      float s64a = 0.f, s64b = 0.f;
      #pragma unroll 8
      for (int k = 0; k < 32; ++k) {
        const float2 w2 = *(const float2*)&Wm[k*68 + j2];
        const float4 q0 = *(const float4*)&Wm[k*68 + c0];
        const float4 q1 = *(const float4*)&Wm[k*68 + c0 + 4];
        a0.x += w2.x*q0.x; a0.y += w2.x*q0.y; a0.z += w2.x*q0.z; a0.w += w2.x*q0.w;
        a1.x += w2.x*q1.x; a1.y += w2.x*q1.y; a1.z += w2.x*q1.z; a1.w += w2.x*q1.w;
        b0a.x += w2.y*q0.x; b0a.y += w2.y*q0.y; b0a.z += w2.y*q0.z; b0a.w += w2.y*q0.w;
        b1a.x += w2.y*q1.x; b1a.y += w2.y*q1.y; b1a.z += w2.y*q1.z; b1a.w += w2.y*q1.w;
        if (do64) { const float wm = Wm[k*68 + 64]; s64a += w2.x*wm; s64b += w2.y*wm; }
      }
      float4 c0a = *(const float4*)&covp[(j2+0)*68 + c0];
      float4 c0b = *(const float4*)&covp[(j2+0)*68 + c0 + 4];
      float4 c1a = *(const float4*)&covp[(j2+1)*68 + c0];
      float4 c1b = *(const float4*)&covp[(j2+1)*68 + c0 + 4];
      c0a.x -= a0.x;  c0a.y -= a0.y;  c0a.z -= a0.z;  c0a.w -= a0.w;
      c0b.x -= a1.x;  c0b.y -= a1.y;  c0b.z -= a1.z;  c0b.w -= a1.w;
      c1a.x -= b0a.x; c1a.y -= b0a.y; c1a.z -= b0a.z; c1a.w -= b0a.w;
      c1b.x -= b1a.x; c1b.y -= b1a.y; c1b.z -= b1a.z; c1b.w -= b1a.w;
      *(float4*)&covs[(size_t)tb*4096 + (j2+0)*64 + c0]     = c0a;
      *(float4*)&covs[(size_t)tb*4096 + (j2+0)*64 + c0 + 4] = c0b;
      *(float4*)&covs[(size_t)tb*4096 + (j2+1)*64 + c0]     = c1a;
      *(float4*)&covs[(size_t)tb*4096 + (j2+1)*64 + c0 + 4] = c1b;
      if (do64) {
        means[(size_t)tb*64 + j2+0] = covp[(j2+0)*68 + 64] - s64a;
        means[(size_t)tb*64 + j2+1] = covp[(j2+1)*68 + 64] - s64b;
      }
    } else {
      const int task = tid - 256;                  // 0..255
      const int a2 = (task >> 4)*2, c0 = (task & 15)*4;
      const float* Wr0 = &Wm[(a2+0)*68];
      const float* Wr1 = &Wm[(a2+1)*68];
      const float* Atc = At[cur];
      float4 acc0 = make_float4(0,0,0,0), acc1 = acc0;
      #pragma unroll 4
      for (int k4 = 0; k4 < 16; ++k4) {
        const float4 w0 = *(const float4*)&Wr0[k4*4];
        const float4 w1 = *(const float4*)&Wr1[k4*4];
        const float4 b0 = *(const float4*)&Atc[(k4*4+0)*68 + c0];
        const float4 b1 = *(const float4*)&Atc[(k4*4+1)*68 + c0];
        const float4 b2 = *(const float4*)&Atc[(k4*4+2)*68 + c0];
        const float4 b3 = *(const float4*)&Atc[(k4*4+3)*68 + c0];
        acc0.x += w0.x*b0.x + w0.y*b1.x + w0.z*b2.x + w0.w*b3.x;
        acc0.y += w0.x*b0.y + w0.y*b1.y + w0.z*b2.y + w0.w*b3.y;
        acc0.z += w0.x*b0.z + w0.y*b1.z + w0.z*b2.z + w0.w*b3.z;
        acc0.w += w0.x*b0.w + w0.y*b1.w + w0.z*b2.w + w0.w*b3.w;
        acc1.x += w1.x*b0.x + w1.y*b1.x + w1.z*b2.x + w1.w*b3.x;
        acc1.y += w1.x*b0.y + w1.y*b1.y + w1.z*b2.y + w1.w*b3.y;
        acc1.z += w1.x*b0.z + w1.y*b1.z + w1.z*b2.z + w1.w*b3.z;
        acc1.w += w1.x*b0.w + w1.y*b1.w + w1.z*b2.w + w1.w*b3.w;
      }
      *(float4*)&Vt[(a2+0)*68 + c0] = acc0;
      *(float4*)&Vt[(a2+1)*68 + c0] = acc1;
    }
    __syncthreads();   // B5
    // ---- PH6: covnext = U A^T - V V^T + Q -> covp; ncovs; mean_next
    //      2x4 tiles: 512 threads x (2 rows x 4 cols)
    {
      const int i2 = (tid >> 4)*2, j0 = (tid & 15)*4;
      const float* Atc = At[cur];
      const float* u0 = &Um[(i2+0)*68];
      const float* u1 = &Um[(i2+1)*68];
      float4 a0 = *(const float4*)&Ql[(i2+0)*68 + j0];
      float4 a1 = *(const float4*)&Ql[(i2+1)*68 + j0];
      #pragma unroll 4
      for (int k4 = 0; k4 < 16; ++k4) {
        const float4 t0 = *(const float4*)&u0[k4*4];
        const float4 t1 = *(const float4*)&u1[k4*4];
        #pragma unroll
        for (int m = 0; m < 4; ++m) {
          const float av0 = (m==0)?t0.x:(m==1)?t0.y:(m==2)?t0.z:t0.w;
          const float av1 = (m==0)?t1.x:(m==1)?t1.y:(m==2)?t1.z:t1.w;
          const float4 bb = *(const float4*)&Atc[(k4*4+m)*68 + j0];
          a0.x += av0*bb.x; a0.y += av0*bb.y; a0.z += av0*bb.z; a0.w += av0*bb.w;
          a1.x += av1*bb.x; a1.y += av1*bb.y; a1.z += av1*bb.z; a1.w += av1*bb.w;
        }
      }
      #pragma unroll 8
      for (int a = 0; a < 32; ++a) {
        const float2 v2 = *(const float2*)&Vt[a*68 + i2];
        const float4 bb = *(const float4*)&Vt[a*68 + j0];
        a0.x -= v2.x*bb.x; a0.y -= v2.x*bb.y; a0.z -= v2.x*bb.z; a0.w -= v2.x*bb.w;
        a1.x -= v2.y*bb.x; a1.y -= v2.y*bb.y; a1.z -= v2.y*bb.z; a1.w -= v2.y*bb.w;
      }
      *(float4*)&covp[(i2+0)*68 + j0] = a0;
      *(float4*)&covp[(i2+1)*68 + j0] = a1;
      *(float4*)&ncovs[(size_t)tb*4096 + (i2+0)*64 + j0] = a0;
      *(float4*)&ncovs[(size_t)tb*4096 + (i2+1)*64 + j0] = a1;
      if ((tid & 15) == 15) {
        float s64a = Um[(i2+0)*68 + 64];           // A @ meanp
        float s64b = Um[(i2+1)*68 + 64];
        #pragma unroll 8
        for (int a = 0; a < 32; ++a) {
          const float2 v2 = *(const float2*)&Vt[a*68 + i2];
          const float wm = Wm[a*68 + 64];
          s64a -= v2.x*wm; s64b -= v2.y*wm;
        }
        covp[(i2+0)*68 + 64] = s64a;               // mean_next
        covp[(i2+1)*68 + 64] = s64b;
        nmeans[(size_t)tb*64 + i2+0] = s64a;
        nmeans[(size_t)tb*64 + i2+1] = s64b;
      }
    }
    __syncthreads();   // B6
    cur = nxt;
  }
}

extern "C" void kernel_launch(void* const* d_in, const int* in_sizes, int n_in,
                              void* d_out, int out_size, void* d_ws, size_t ws_size,
                              hipStream_t stream) {
  const float* as_  = (const float*)d_in[0];
  const float* AK   = (const float*)d_in[1];
  const float* CK   = (const float*)d_in[2];
  const float* QL   = (const float*)d_in[3];
  const float* RL   = (const float*)d_in[4];
  const float* linW = (const float*)d_in[5];
  const float* linb = (const float*)d_in[6];
  const float* Wih0 = (const float*)d_in[7];
  const float* Whh0 = (const float*)d_in[8];
  const float* bih0 = (const float*)d_in[9];
  const float* bhh0 = (const float*)d_in[10];
  const float* Wih1 = (const float*)d_in[11];
  const float* Whh1 = (const float*)d_in[12];
  const float* bih1 = (const float*)d_in[13];
  const float* bhh1 = (const float*)d_in[14];
  float* out = (float*)d_out;
  float* ws  = (float*)d_ws;

  prep_kernel<<<856, 256, 0, stream>>>(Wih0, Whh0, bih0, bhh0,
                                       Wih1, Whh1, bih1, bhh1, QL, RL, ws);
  lstm_kernel<<<B_SZ, 1024, 0, stream>>>(as_, ws, linW, linb, ws + WS_W);
  mix_kernel<<<(T_LEN*B_SZ)/16, 256, 0, stream>>>(ws + WS_W, AK, CK, out);
  kalman_kernel<<<B_SZ, 512, 0, stream>>>(as_, ws, out);
}